// Round 5
// baseline (2093.856 us; speedup 1.0000x reference)
//
#include <hip/hip_runtime.h>
#include <hip/hip_cooperative_groups.h>
#include <math.h>

namespace cg = cooperative_groups;

// GARNN persistent-cooperative kernel. B=16, N=512, U=64, SEQ=HORIZON=12, f32.
// One kernel, 256 blocks x 1024 threads (1 block/CU, guaranteed co-resident),
// 2 nodes/wave, grid.sync() between phases. Weights staged to LDS twice total
// (enc at entry, dec at cell 11). h/u/src/y live in registers across cells.

#define NB 16
#define NN 512
#define NU 64
#define CAP 128
#define NBLK 256
#define NWAVE 16    // waves per block

#define AS1 __attribute__((address_space(1)))
#define AS3 __attribute__((address_space(3)))

__device__ __forceinline__ void ld_lds16(float* lds_u, const float* g) {
#if __has_builtin(__builtin_amdgcn_global_load_lds)
  __builtin_amdgcn_global_load_lds((const AS1 unsigned int*)g,
                                   (AS3 unsigned int*)lds_u, 16, 0, 0);
#else
  int lane = threadIdx.x & 63;
  *(float4*)(lds_u + lane * 4) = *(const float4*)g;
#endif
}
// Stage TB bytes into sW; wave w takes chunks w, w+16, ... (1 KB each).
__device__ __forceinline__ void stage_weights(float* sW, const float* W, int TB,
                                              int w, int lane) {
  for (int c = w; c * 1024 < TB; c += NWAVE) {
    int off = c * 1024 + lane * 16;
    if (off < TB)
      ld_lds16((float*)((char*)sW + c * 1024), (const float*)((const char*)W + off));
  }
}

__device__ __forceinline__ float rlane(float v, int l) {
  return __int_as_float(__builtin_amdgcn_readlane(__float_as_int(v), l));
}
__device__ __forceinline__ int rlane_i(int v, int l) {
  return __builtin_amdgcn_readlane(v, l);
}
__device__ __forceinline__ float wave_max(float v) {
  #pragma unroll
  for (int s = 1; s < 64; s <<= 1) v = fmaxf(v, __shfl_xor(v, s));
  return v;
}
__device__ __forceinline__ float wave_sum(float v) {
  #pragma unroll
  for (int s = 1; s < 64; s <<= 1) v += __shfl_xor(v, s);
  return v;
}
__device__ __forceinline__ void wave_sum2(float& x, float& y) {
  #pragma unroll
  for (int s = 1; s < 64; s <<= 1) { x += __shfl_xor(x, s); y += __shfl_xor(y, s); }
}
__device__ __forceinline__ float fast_rcp(float x) {
#if __has_builtin(__builtin_amdgcn_rcpf)
  return __builtin_amdgcn_rcpf(x);
#else
  return 1.0f / x;
#endif
}
__device__ __forceinline__ float sigmoid_f(float x) {
  return fast_rcp(1.0f + __expf(-x));
}
__device__ __forceinline__ float tanh_f(float x) {
  return 1.0f - 2.0f * fast_rcp(__expf(2.0f * x) + 1.0f);
}

// Neighbor lists: mask[i][j] = adj[i][j] > 0.9 || i == j; pad tail with j=i.
__global__ __launch_bounds__(64) void k_adj(const float* __restrict__ adj,
                                            int* __restrict__ cnt,
                                            int* __restrict__ idx) {
  int i = blockIdx.x;
  int l = threadIdx.x;
  int base = 0;
  #pragma unroll
  for (int c = 0; c < 8; ++c) {
    int j = c * 64 + l;
    bool pred = (adj[i * NN + j] > 0.9f) || (j == i);
    unsigned long long m = __ballot(pred);
    int pos = base + __popcll(m & ((1ull << l) - 1ull));
    if (pred && pos < CAP) idx[i * CAP + pos] = j;
    base += __popcll(m);
  }
  int total = base > CAP ? CAP : base;
  for (int p = total + l; p < CAP; p += 64) idx[i * CAP + p] = i;
  if (l == 0) cnt[i] = total;
}

__global__ __launch_bounds__(1024, 4) void k_garnn(
    const float* __restrict__ inputs,
    const int* __restrict__ cnt, const int* __restrict__ idx,
    const float* __restrict__ enc_W_ru, const float* __restrict__ enc_a_ru,
    const float* __restrict__ enc_b_ru, const float* __restrict__ enc_W_c,
    const float* __restrict__ enc_a_c, const float* __restrict__ enc_b_c,
    const float* __restrict__ dec_W_ru, const float* __restrict__ dec_a_ru,
    const float* __restrict__ dec_b_ru, const float* __restrict__ dec_W_c,
    const float* __restrict__ dec_a_c, const float* __restrict__ dec_b_c,
    const float* __restrict__ proj_W, const float* __restrict__ proj_b,
    float* __restrict__ h_ru, float* __restrict__ dst_ru_g,
    float* __restrict__ h_c, float* __restrict__ dst_c_g,
    float* __restrict__ out) {
  __shared__ float sWru[8448];   // 33792 B (enc: (2+64)x128; dec uses 33280 B)
  __shared__ float sWc[4224];    // 16896 B (enc: 66x64; dec uses 16640 B)
  cg::grid_group grid = cg::this_grid();
  const int tid = threadIdx.x, w = tid >> 6, lane = tid & 63;

  stage_weights(sWru, enc_W_ru, 33792, w, lane);
  stage_weights(sWc, enc_W_c, 16896, w, lane);

  const int wave_gid = blockIdx.x * NWAVE + w;   // 0..4095; nodes 2*wg, 2*wg+1
  int bi_[2], b_[2], c_[2], j0_[2], j1_[2];
  float hn_[2] = {0.f, 0.f};
  float src_ru_[2], src_c_[2], u_[2];
  float y_[2] = {0.f, 0.f};   // stays 0 until first decoder projection (= GO)
  #pragma unroll
  for (int n = 0; n < 2; ++n) {
    int bi = 2 * wave_gid + n;
    int i = bi & 511;
    bi_[n] = bi; b_[n] = bi >> 9;
    c_[n] = cnt[i];
    j0_[n] = idx[(i << 7) + lane];
    j1_[n] = idx[(i << 7) + 64 + lane];
  }
  __syncthreads();   // weight stage drained (compiler emits vmcnt(0) at barrier)

  // ---- init: h = 0; h_ru = [x_0, 0] @ enc_W_ru; src/dst_ru ----
  #pragma unroll
  for (int n = 0; n < 2; ++n) {
    const float2 xv = *(const float2*)(inputs + (size_t)bi_[n] * 2);
    const int g0 = lane << 1;
    float a0 = xv.x * sWru[g0] + xv.y * sWru[128 + g0];
    float a1 = xv.x * sWru[g0 + 1] + xv.y * sWru[128 + g0 + 1];
    *(float2*)(h_ru + ((size_t)bi_[n] << 7) + g0) = make_float2(a0, a1);
    const float2 ar0 = *(const float2*)(enc_a_ru + g0);
    const float2 ar1 = *(const float2*)(enc_a_ru + 128 + g0);
    float s0 = a0 * ar0.x + a1 * ar0.y;
    float s1 = a0 * ar1.x + a1 * ar1.y;
    wave_sum2(s0, s1);
    src_ru_[n] = s0;
    if (lane == 0) dst_ru_g[bi_[n]] = s1;
  }
  grid.sync();

  for (int cell = 0; cell < 24; ++cell) {
    const bool enc = cell < 12;
    const float* b_ru_p = enc ? enc_b_ru : dec_b_ru;
    const float* a_c_p  = enc ? enc_a_c  : dec_a_c;
    const float* b_c_p  = enc ? enc_b_c  : dec_b_c;

    // ================= phase B: ru-attention + h_c GEMV =================
    #pragma unroll
    for (int n = 0; n < 2; ++n) {
      const int b = b_[n], bi = bi_[n], cN = c_[n];
      const float* __restrict__ hrb = h_ru + ((size_t)b << 16);
      const float* __restrict__ drb = dst_ru_g + (b << 9);
      const float si = src_ru_[n];
      float x0, x1 = 0.f;
      if (enc) {
        float2 xv = *(const float2*)(inputs + (size_t)cell * 16384 + (size_t)bi * 2);
        x0 = xv.x; x1 = xv.y;
      } else {
        x0 = y_[n];   // decoder input: previous y (y_== 0 at cell 12 -> GO)
      }
      float e0 = -1e30f, e1 = -1e30f;
      if (lane < cN)      { float t = si + drb[j0_[n]]; e0 = t >= 0.f ? t : 0.2f * t; }
      if (lane + 64 < cN) { float t = si + drb[j1_[n]]; e1 = t >= 0.f ? t : 0.2f * t; }
      float m = wave_max(fmaxf(e0, e1));
      float p0 = (lane < cN) ? __expf(e0 - m) : 0.f;
      float p1 = (lane + 64 < cN) ? __expf(e1 - m) : 0.f;
      float inv = fast_rcp(wave_sum(p0 + p1));
      p0 *= inv; p1 *= inv;

      const int g0 = lane << 1;
      float A0 = 0.f, A1 = 0.f, B0 = 0.f, B1 = 0.f;
      const int ccn = (cN + 15) & ~15;
      for (int base = 0; base < ccn; base += 16) {
        float2 hv[16];
        #pragma unroll
        for (int q = 0; q < 16; ++q) {
          int jj = base + q; int sl = jj & 63;
          int j = (jj < 64) ? rlane_i(j0_[n], sl) : rlane_i(j1_[n], sl);
          hv[q] = *(const float2*)(hrb + (j << 7) + g0);
        }
        #pragma unroll
        for (int q = 0; q < 16; ++q) {
          int jj = base + q; int sl = jj & 63;
          float pv = (jj < 64) ? rlane(p0, sl) : rlane(p1, sl);
          if (q & 1) { B0 = fmaf(pv, hv[q].x, B0); B1 = fmaf(pv, hv[q].y, B1); }
          else       { A0 = fmaf(pv, hv[q].x, A0); A1 = fmaf(pv, hv[q].y, A1); }
        }
      }
      A0 += B0; A1 += B1;

      const float2 br = *(const float2*)(b_ru_p + g0);
      const float ru0 = sigmoid_f(A0 + br.x);
      const float ru1 = sigmoid_f(A1 + br.y);
      // remap: feature f=lane; r[f] from lane f>>1 (r: lanes 0..31), u[f] from 32+(f>>1)
      float rs0 = __shfl(ru0, lane >> 1), rs1 = __shfl(ru1, lane >> 1);
      float r_l = (lane & 1) ? rs1 : rs0;
      float us0 = __shfl(ru0, 32 + (lane >> 1)), us1 = __shfl(ru1, 32 + (lane >> 1));
      u_[n] = (lane & 1) ? us1 : us0;
      const float rh = r_l * hn_[n];

      // h_c GEMV: xc = [x, r*h]; output feature = lane
      float acc = x0 * sWc[lane];
      if (enc) acc = fmaf(x1, sWc[NU + lane], acc);
      const float* __restrict__ sWh = sWc + (enc ? 2 : 1) * NU;
      #pragma unroll
      for (int f = 0; f < NU; ++f)
        acc = fmaf(rlane(rh, f), sWh[f * NU + lane], acc);
      h_c[((size_t)bi << 6) + lane] = acc;
      float s0 = acc * a_c_p[lane];
      float s1 = acc * a_c_p[NU + lane];
      wave_sum2(s0, s1);
      src_c_[n] = s0;
      if (lane == 0) dst_c_g[bi] = s1;
    }

    if (cell == 11) {  // switch to decoder weights (phaseA(11) builds dec h_ru)
      __syncthreads();                               // everyone done reading enc
      stage_weights(sWru, dec_W_ru, 33280, w, lane);
      stage_weights(sWc, dec_W_c, 16640, w, lane);
      __syncthreads();                               // staged + drained
    }
    grid.sync();

    // ====== phase A: c-attention, h update, (proj), next h_ru GEMV ======
    const bool lastCell = (cell == 23);
    const float* a_ru_p = (cell < 11) ? enc_a_ru : dec_a_ru;
    #pragma unroll
    for (int n = 0; n < 2; ++n) {
      const int b = b_[n], bi = bi_[n], cN = c_[n];
      const float* __restrict__ hcb = h_c + ((size_t)b << 15);
      const float* __restrict__ dcb = dst_c_g + (b << 9);
      const float si = src_c_[n];
      float e0 = -1e30f, e1 = -1e30f;
      if (lane < cN)      { float t = si + dcb[j0_[n]]; e0 = t >= 0.f ? t : 0.2f * t; }
      if (lane + 64 < cN) { float t = si + dcb[j1_[n]]; e1 = t >= 0.f ? t : 0.2f * t; }
      float m = wave_max(fmaxf(e0, e1));
      float p0 = (lane < cN) ? __expf(e0 - m) : 0.f;
      float p1 = (lane + 64 < cN) ? __expf(e1 - m) : 0.f;
      float inv = fast_rcp(wave_sum(p0 + p1));
      p0 *= inv; p1 *= inv;

      float A = 0.f, Bc = 0.f;
      const int ccn = (cN + 15) & ~15;
      for (int base = 0; base < ccn; base += 16) {
        float hv[16];
        #pragma unroll
        for (int q = 0; q < 16; ++q) {
          int jj = base + q; int sl = jj & 63;
          int j = (jj < 64) ? rlane_i(j0_[n], sl) : rlane_i(j1_[n], sl);
          hv[q] = hcb[(j << 6) + lane];
        }
        #pragma unroll
        for (int q = 0; q < 16; ++q) {
          int jj = base + q; int sl = jj & 63;
          float pv = (jj < 64) ? rlane(p0, sl) : rlane(p1, sl);
          if (q & 1) Bc = fmaf(pv, hv[q], Bc);
          else       A  = fmaf(pv, hv[q], A);
        }
      }
      A += Bc;
      const float ccv = tanh_f(A + b_c_p[lane]);
      const float hn_new = fmaf(u_[n], hn_[n] - ccv, ccv);  // u*h + (1-u)*c
      hn_[n] = hn_new;

      if (!enc) {  // decoder: project y and emit output
        float t = wave_sum(hn_new * proj_W[lane]);
        float yv = t + proj_b[0];
        y_[n] = yv;
        if (lane == 0) out[(size_t)(cell - 12) * (NB * NN) + bi] = yv;
      }

      if (!lastCell) {
        const int g0 = lane << 1;
        float x0n = 0.f, x1n = 0.f;
        if (cell < 11) {
          float2 xv = *(const float2*)(inputs + (size_t)(cell + 1) * 16384 + (size_t)bi * 2);
          x0n = xv.x; x1n = xv.y;
        } else if (cell >= 12) {
          x0n = y_[n];
        }  // cell==11: GO token -> zeros
        float a0 = x0n * sWru[g0], a1 = x0n * sWru[g0 + 1];
        if (cell < 11) {
          a0 = fmaf(x1n, sWru[128 + g0], a0);
          a1 = fmaf(x1n, sWru[128 + g0 + 1], a1);
        }
        const float* __restrict__ sWh = sWru + ((cell < 11) ? 2 : 1) * 128;
        #pragma unroll
        for (int f = 0; f < NU; ++f) {
          float hv = rlane(hn_new, f);
          float2 wv = *(const float2*)(sWh + f * 128 + g0);
          a0 = fmaf(hv, wv.x, a0);
          a1 = fmaf(hv, wv.y, a1);
        }
        *(float2*)(h_ru + ((size_t)bi << 7) + g0) = make_float2(a0, a1);
        const float2 ar0 = *(const float2*)(a_ru_p + g0);
        const float2 ar1 = *(const float2*)(a_ru_p + 128 + g0);
        float s0 = a0 * ar0.x + a1 * ar0.y;
        float s1 = a0 * ar1.x + a1 * ar1.y;
        wave_sum2(s0, s1);
        src_ru_[n] = s0;
        if (lane == 0) dst_ru_g[bi] = s1;
      }
    }
    if (!lastCell) grid.sync();
  }
}

extern "C" void kernel_launch(void* const* d_in, const int* in_sizes, int n_in,
                              void* d_out, int out_size, void* d_ws, size_t ws_size,
                              hipStream_t stream) {
  (void)in_sizes; (void)n_in; (void)out_size; (void)ws_size;
  const float* inputs   = (const float*)d_in[0];
  const float* adj      = (const float*)d_in[1];
  const float* enc_W_ru = (const float*)d_in[2];
  const float* enc_a_ru = (const float*)d_in[3];
  const float* enc_b_ru = (const float*)d_in[4];
  const float* enc_W_c  = (const float*)d_in[5];
  const float* enc_a_c  = (const float*)d_in[6];
  const float* enc_b_c  = (const float*)d_in[7];
  const float* dec_W_ru = (const float*)d_in[8];
  const float* dec_a_ru = (const float*)d_in[9];
  const float* dec_b_ru = (const float*)d_in[10];
  const float* dec_W_c  = (const float*)d_in[11];
  const float* dec_a_c  = (const float*)d_in[12];
  const float* dec_b_c  = (const float*)d_in[13];
  const float* proj_W   = (const float*)d_in[14];
  const float* proj_b   = (const float*)d_in[15];
  float* out = (float*)d_out;

  char* ws = (char*)d_ws;
  int*   cnt    = (int*)ws;                    // 2048 B
  int*   idx    = (int*)(ws + 2048);           // 262144 B
  float* h_ru   = (float*)(ws + 264192);       // 4194304 B
  float* h_c    = (float*)(ws + 4458496);      // 2097152 B
  float* dst_ru = (float*)(ws + 6555648);      // 32768 B
  float* dst_c  = (float*)(ws + 6588416);      // 32768 B (end 6621184)

  k_adj<<<NN, 64, 0, stream>>>(adj, cnt, idx);

  void* args[] = {
    (void*)&inputs, (void*)&cnt, (void*)&idx,
    (void*)&enc_W_ru, (void*)&enc_a_ru, (void*)&enc_b_ru,
    (void*)&enc_W_c,  (void*)&enc_a_c,  (void*)&enc_b_c,
    (void*)&dec_W_ru, (void*)&dec_a_ru, (void*)&dec_b_ru,
    (void*)&dec_W_c,  (void*)&dec_a_c,  (void*)&dec_b_c,
    (void*)&proj_W, (void*)&proj_b,
    (void*)&h_ru, (void*)&dst_ru, (void*)&h_c, (void*)&dst_c,
    (void*)&out
  };
  hipLaunchCooperativeKernel((const void*)k_garnn, dim3(NBLK), dim3(1024),
                             args, 0, stream);
}

// Round 6
// 1032.550 us; speedup vs baseline: 2.0279x; 2.0279x over previous
//
#include <hip/hip_runtime.h>
#include <math.h>

// GARNN: graph-attention GRU, B=16, N=512, U=64, SEQ=12, HORIZON=12, all f32.
// 2 kernels per cell (phaseB = ru-attention + h_c GEMV; phaseA = c-attention +
// state update + proj + next cell's h_ru). R6: revert to R4 multi-kernel (coop
// regressed: latency-bound, per-wave serial work doubled). New: double-buffered
// 8+8 gather (8 loads in flight during FMAs), launch_bounds(512,8) -> 4 blk/CU.

#define NB 16
#define NN 512
#define NU 64
#define CAP 128   // neighbor-list capacity (Bin(511,0.1) max << 128)
#define WPB 8     // waves (=nodes) per block

#define AS1 __attribute__((address_space(1)))
#define AS3 __attribute__((address_space(3)))

__device__ __forceinline__ void ld_lds16(float* lds_uniform, const float* g_perlane) {
#if __has_builtin(__builtin_amdgcn_global_load_lds)
  __builtin_amdgcn_global_load_lds((const AS1 unsigned int*)g_perlane,
                                   (AS3 unsigned int*)lds_uniform, 16, 0, 0);
#else
  int lane = threadIdx.x & 63;
  *(float4*)(lds_uniform + lane * 4) = *(const float4*)(g_perlane);
#endif
}

// Async-stage TB bytes of weights into sW. Wave w handles chunks c = w, w+8, ...
__device__ __forceinline__ void stage_weights(float* sW, const float* W, int TB,
                                              int w, int lane) {
  for (int c = w; c * 1024 < TB; c += WPB) {
    int off = c * 1024 + lane * 16;
    if (off < TB)
      ld_lds16((float*)((char*)sW + c * 1024), (const float*)((const char*)W + off));
  }
}

__device__ __forceinline__ float rlane(float v, int l) {
  return __int_as_float(__builtin_amdgcn_readlane(__float_as_int(v), l));
}
__device__ __forceinline__ int rlane_i(int v, int l) {
  return __builtin_amdgcn_readlane(v, l);
}
__device__ __forceinline__ float wave_max(float v) {
  #pragma unroll
  for (int s = 1; s < 64; s <<= 1) v = fmaxf(v, __shfl_xor(v, s));
  return v;
}
__device__ __forceinline__ float wave_sum(float v) {
  #pragma unroll
  for (int s = 1; s < 64; s <<= 1) v += __shfl_xor(v, s);
  return v;
}
__device__ __forceinline__ void wave_sum2(float& x, float& y) {
  #pragma unroll
  for (int s = 1; s < 64; s <<= 1) { x += __shfl_xor(x, s); y += __shfl_xor(y, s); }
}
__device__ __forceinline__ float fast_rcp(float x) {
#if __has_builtin(__builtin_amdgcn_rcpf)
  return __builtin_amdgcn_rcpf(x);
#else
  return 1.0f / x;
#endif
}
__device__ __forceinline__ float sigmoid_f(float x) {
  return fast_rcp(1.0f + __expf(-x));
}
__device__ __forceinline__ float tanh_f(float x) {
  return 1.0f - 2.0f * fast_rcp(__expf(2.0f * x) + 1.0f);
}

// Neighbor lists: mask[i][j] = adj[i][j] > 0.9 || i == j, ascending j.
// Pad tail [cnt, CAP) with j=i so gather loops run unpredicated (p=0 there).
__global__ __launch_bounds__(64) void k_adj(const float* __restrict__ adj,
                                            int* __restrict__ cnt,
                                            int* __restrict__ idx) {
  int i = blockIdx.x;
  int l = threadIdx.x;
  int base = 0;
  #pragma unroll
  for (int c = 0; c < 8; ++c) {
    int j = c * 64 + l;
    bool pred = (adj[i * NN + j] > 0.9f) || (j == i);
    unsigned long long m = __ballot(pred);
    int pos = base + __popcll(m & ((1ull << l) - 1ull));
    if (pred && pos < CAP) idx[i * CAP + pos] = j;
    base += __popcll(m);
  }
  int total = base > CAP ? CAP : base;
  for (int p = total + l; p < CAP; p += 64) idx[i * CAP + p] = i;  // pad
  if (l == 0) cnt[i] = total;
}

// Phase B: ru-attention -> r,u ; write u; h_c = [x, r*h] @ W_c; src_c/dst_c.
template <int DIN>
__global__ __launch_bounds__(512, 8) void k_phaseB(
    const int* __restrict__ cnt, const int* __restrict__ idx,
    const float* __restrict__ h_ru, const float* __restrict__ src_ru,
    const float* __restrict__ dst_ru, const float* __restrict__ b_ru,
    const float* __restrict__ h, const float* __restrict__ x_ptr,
    const float* __restrict__ W_c, const float* __restrict__ a_c,
    float* __restrict__ h_c, float* __restrict__ src_c,
    float* __restrict__ dst_c, float* __restrict__ u_buf) {
  constexpr int TB = (DIN + NU) * NU * 4;
  __shared__ float sW[(DIN + NU) * NU];
  __shared__ float sh[WPB * NU];    // per-wave r*h broadcast
  const int tid = threadIdx.x;
  const int w = tid >> 6, lane = tid & 63;

  stage_weights(sW, W_c, TB, w, lane);   // async; drained at the barrier below

  const int b = blockIdx.x >> 6;                 // block-uniform -> SGPR bases
  const int i = ((blockIdx.x & 63) << 3) | w;
  const int base_bi = (b << 9) + i;
  const float* __restrict__ hrb = h_ru + ((size_t)b << 16);
  const float* __restrict__ drb = dst_ru + (b << 9);

  const int c_ = cnt[i];
  const float si = src_ru[base_bi];
  const int j0 = idx[(i << 7) + lane];
  const int j1 = idx[(i << 7) + 64 + lane];
  float e0 = -1e30f, e1 = -1e30f;
  if (lane < c_)      { float t = si + drb[j0]; e0 = t >= 0.f ? t : 0.2f * t; }
  if (lane + 64 < c_) { float t = si + drb[j1]; e1 = t >= 0.f ? t : 0.2f * t; }
  float m = wave_max(fmaxf(e0, e1));
  float p0 = (lane < c_) ? __expf(e0 - m) : 0.f;
  float p1 = (lane + 64 < c_) ? __expf(e1 - m) : 0.f;
  float inv = fast_rcp(wave_sum(p0 + p1));
  p0 *= inv; p1 *= inv;

  // aggregation over neighbors, double-buffered 8+8: 8 loads in flight
  // while 8 FMA. FMA order identical to R4 (even jj -> A, odd -> B).
  const int g0 = lane << 1;
  float A0 = 0.f, A1 = 0.f, B0 = 0.f, B1 = 0.f;
  const int ccn = (c_ + 15) & ~15;
  float2 va[8], vb[8];
  #pragma unroll
  for (int q = 0; q < 8; ++q) {          // prologue: jj = 0..7
    int j = rlane_i(j0, q);
    va[q] = *(const float2*)(hrb + (j << 7) + g0);
  }
  for (int base = 0; base < ccn; base += 16) {
    #pragma unroll
    for (int q = 0; q < 8; ++q) {        // load jj = base+8..base+15
      int jj = base + 8 + q; int sl = jj & 63;
      int j = (jj < 64) ? rlane_i(j0, sl) : rlane_i(j1, sl);
      vb[q] = *(const float2*)(hrb + (j << 7) + g0);
    }
    #pragma unroll
    for (int q = 0; q < 8; ++q) {        // fma jj = base..base+7
      int jj = base + q; int sl = jj & 63;
      float pv = (jj < 64) ? rlane(p0, sl) : rlane(p1, sl);
      if (q & 1) { B0 = fmaf(pv, va[q].x, B0); B1 = fmaf(pv, va[q].y, B1); }
      else       { A0 = fmaf(pv, va[q].x, A0); A1 = fmaf(pv, va[q].y, A1); }
    }
    if (base + 16 < ccn) {
      #pragma unroll
      for (int q = 0; q < 8; ++q) {      // load jj = base+16..base+23
        int jj = base + 16 + q; int sl = jj & 63;
        int j = (jj < 64) ? rlane_i(j0, sl) : rlane_i(j1, sl);
        va[q] = *(const float2*)(hrb + (j << 7) + g0);
      }
    }
    #pragma unroll
    for (int q = 0; q < 8; ++q) {        // fma jj = base+8..base+15
      int jj = base + 8 + q; int sl = jj & 63;
      float pv = (jj < 64) ? rlane(p0, sl) : rlane(p1, sl);
      if (q & 1) { B0 = fmaf(pv, vb[q].x, B0); B1 = fmaf(pv, vb[q].y, B1); }
      else       { A0 = fmaf(pv, vb[q].x, A0); A1 = fmaf(pv, vb[q].y, A1); }
    }
  }
  A0 += B0; A1 += B1;

  const float2 br = *(const float2*)(b_ru + g0);
  const float ru0 = sigmoid_f(A0 + br.x);
  const float ru1 = sigmoid_f(A1 + br.y);

  // lanes 0..31: r (g<64) -> r*h into LDS; lanes 32..63: u -> global
  if (lane < 32) {
    float2 hh = *(const float2*)(h + ((size_t)base_bi << 6) + g0);
    *(float2*)&sh[(w << 6) + g0] = make_float2(ru0 * hh.x, ru1 * hh.y);
  } else {
    *(float2*)(u_buf + ((size_t)base_bi << 6) + (g0 - 64)) = make_float2(ru0, ru1);
  }

  __syncthreads();   // drains async weight stage + sh visibility

  // h_c GEMV over xc = [x, r*h]; output feature = lane
  float acc;
  if (DIN == 2) {
    float2 xv = *(const float2*)(x_ptr + ((size_t)base_bi << 1));
    acc = xv.x * sW[lane];
    acc = fmaf(xv.y, sW[NU + lane], acc);
  } else {
    acc = x_ptr[base_bi] * sW[lane];
  }
  const float* __restrict__ sWh = sW + DIN * NU;
  const float* shw = sh + (w << 6);
  #pragma unroll
  for (int f2 = 0; f2 < 32; ++f2) {
    float2 rv = *(const float2*)(shw + 2 * f2);   // b64 broadcast
    acc = fmaf(rv.x, sWh[(2 * f2) * NU + lane], acc);
    acc = fmaf(rv.y, sWh[(2 * f2 + 1) * NU + lane], acc);
  }
  h_c[((size_t)base_bi << 6) + lane] = acc;
  float s0 = acc * a_c[lane];
  float s1 = acc * a_c[NU + lane];
  wave_sum2(s0, s1);
  if (lane == 0) { src_c[base_bi] = s0; dst_c[base_bi] = s1; }
}

// Phase A: c-attention -> c; h_new = u*h + (1-u)*c (UPD) or 0 (init);
// OUT: proj -> out+y_buf; DIN_NEXT>0: next cell h_ru = [x_next, h_new] @ W_ru.
template <int UPD, int DIN_NEXT, int XMODE, int OUT>
__global__ __launch_bounds__(512, 8) void k_phaseA(
    const int* __restrict__ cnt, const int* __restrict__ idx,
    const float* __restrict__ h_c, const float* __restrict__ src_c,
    const float* __restrict__ dst_c, const float* __restrict__ b_c,
    const float* __restrict__ u_buf, float* __restrict__ h,
    const float* __restrict__ proj_W, const float* __restrict__ proj_b,
    float* __restrict__ out_slice, float* __restrict__ y_buf,
    const float* __restrict__ x_ptr,
    const float* __restrict__ W_ru, const float* __restrict__ a_ru,
    float* __restrict__ h_ru, float* __restrict__ src_ru,
    float* __restrict__ dst_ru) {
  constexpr int SWN = (DIN_NEXT > 0) ? (DIN_NEXT + NU) * 128 : 1;
  constexpr int TB = (DIN_NEXT > 0) ? SWN * 4 : 0;
  __shared__ float sW[SWN];
  __shared__ float sh[WPB * NU];
  const int tid = threadIdx.x;
  const int w = tid >> 6, lane = tid & 63;

  if (DIN_NEXT > 0) stage_weights(sW, W_ru, TB, w, lane);  // async

  const int b = blockIdx.x >> 6;
  const int i = ((blockIdx.x & 63) << 3) | w;
  const int base_bi = (b << 9) + i;

  float hn = 0.f;
  if (UPD) {
    const float* __restrict__ hcb = h_c + ((size_t)b << 15);
    const float* __restrict__ dcb = dst_c + (b << 9);
    const int c_ = cnt[i];
    const float si = src_c[base_bi];
    const int j0 = idx[(i << 7) + lane];
    const int j1 = idx[(i << 7) + 64 + lane];
    float e0 = -1e30f, e1 = -1e30f;
    if (lane < c_)      { float t = si + dcb[j0]; e0 = t >= 0.f ? t : 0.2f * t; }
    if (lane + 64 < c_) { float t = si + dcb[j1]; e1 = t >= 0.f ? t : 0.2f * t; }
    float m = wave_max(fmaxf(e0, e1));
    float p0 = (lane < c_) ? __expf(e0 - m) : 0.f;
    float p1 = (lane + 64 < c_) ? __expf(e1 - m) : 0.f;
    float inv = fast_rcp(wave_sum(p0 + p1));
    p0 *= inv; p1 *= inv;

    float A = 0.f, Bacc = 0.f;
    const int ccn = (c_ + 15) & ~15;
    float va[8], vb[8];
    #pragma unroll
    for (int q = 0; q < 8; ++q) {        // prologue: jj = 0..7
      int j = rlane_i(j0, q);
      va[q] = hcb[(j << 6) + lane];
    }
    for (int base = 0; base < ccn; base += 16) {
      #pragma unroll
      for (int q = 0; q < 8; ++q) {
        int jj = base + 8 + q; int sl = jj & 63;
        int j = (jj < 64) ? rlane_i(j0, sl) : rlane_i(j1, sl);
        vb[q] = hcb[(j << 6) + lane];
      }
      #pragma unroll
      for (int q = 0; q < 8; ++q) {
        int jj = base + q; int sl = jj & 63;
        float pv = (jj < 64) ? rlane(p0, sl) : rlane(p1, sl);
        if (q & 1) Bacc = fmaf(pv, va[q], Bacc);
        else       A = fmaf(pv, va[q], A);
      }
      if (base + 16 < ccn) {
        #pragma unroll
        for (int q = 0; q < 8; ++q) {
          int jj = base + 16 + q; int sl = jj & 63;
          int j = (jj < 64) ? rlane_i(j0, sl) : rlane_i(j1, sl);
          va[q] = hcb[(j << 6) + lane];
        }
      }
      #pragma unroll
      for (int q = 0; q < 8; ++q) {
        int jj = base + 8 + q; int sl = jj & 63;
        float pv = (jj < 64) ? rlane(p0, sl) : rlane(p1, sl);
        if (q & 1) Bacc = fmaf(pv, vb[q], Bacc);
        else       A = fmaf(pv, vb[q], A);
      }
    }
    A += Bacc;
    const float cc_ = tanh_f(A + b_c[lane]);
    const float u = u_buf[((size_t)base_bi << 6) + lane];
    const float ho = h[((size_t)base_bi << 6) + lane];
    hn = fmaf(u, ho - cc_, cc_);   // u*ho + (1-u)*cc
  }
  h[((size_t)base_bi << 6) + lane] = hn;
  sh[(w << 6) + lane] = hn;        // wave-private broadcast buffer

  float y = 0.f;
  if (OUT) {
    float t = wave_sum(hn * proj_W[lane]);
    y = t + proj_b[0];
    if (lane == 0) { out_slice[base_bi] = y; y_buf[base_bi] = y; }
  }

  if (DIN_NEXT > 0) {
    __syncthreads();   // drains async weight stage; sh written above
    const int g0 = lane << 1;
    float a0, a1;
    if (XMODE == 0) {
      if (DIN_NEXT == 2) {
        float2 xv = *(const float2*)(x_ptr + ((size_t)base_bi << 1));
        a0 = xv.x * sW[g0];
        a1 = xv.x * sW[g0 + 1];
        a0 = fmaf(xv.y, sW[128 + g0], a0);
        a1 = fmaf(xv.y, sW[128 + g0 + 1], a1);
      } else {
        float xv = x_ptr[base_bi];
        a0 = xv * sW[g0]; a1 = xv * sW[g0 + 1];
      }
    } else if (XMODE == 2) {
      a0 = y * sW[g0]; a1 = y * sW[g0 + 1];
    } else {  // XMODE==1: decoder GO token (zeros)
      a0 = 0.f; a1 = 0.f;
    }
    const float* __restrict__ sWh = sW + DIN_NEXT * 128;
    const float* shw = sh + (w << 6);
    #pragma unroll
    for (int f2 = 0; f2 < 32; ++f2) {
      float2 hp = *(const float2*)(shw + 2 * f2);          // b64 broadcast
      float2 w0 = *(const float2*)(sWh + (2 * f2) * 128 + g0);
      float2 w1 = *(const float2*)(sWh + (2 * f2 + 1) * 128 + g0);
      a0 = fmaf(hp.x, w0.x, a0); a1 = fmaf(hp.x, w0.y, a1);
      a0 = fmaf(hp.y, w1.x, a0); a1 = fmaf(hp.y, w1.y, a1);
    }
    *(float2*)(h_ru + ((size_t)base_bi << 7) + g0) = make_float2(a0, a1);
    const float2 ar0 = *(const float2*)(a_ru + g0);
    const float2 ar1 = *(const float2*)(a_ru + 128 + g0);
    float s0 = a0 * ar0.x + a1 * ar0.y;
    float s1 = a0 * ar1.x + a1 * ar1.y;
    wave_sum2(s0, s1);
    if (lane == 0) { src_ru[base_bi] = s0; dst_ru[base_bi] = s1; }
  }
}

extern "C" void kernel_launch(void* const* d_in, const int* in_sizes, int n_in,
                              void* d_out, int out_size, void* d_ws, size_t ws_size,
                              hipStream_t stream) {
  (void)in_sizes; (void)n_in; (void)out_size; (void)ws_size;
  const float* inputs   = (const float*)d_in[0];
  const float* adj      = (const float*)d_in[1];
  const float* enc_W_ru = (const float*)d_in[2];
  const float* enc_a_ru = (const float*)d_in[3];
  const float* enc_b_ru = (const float*)d_in[4];
  const float* enc_W_c  = (const float*)d_in[5];
  const float* enc_a_c  = (const float*)d_in[6];
  const float* enc_b_c  = (const float*)d_in[7];
  const float* dec_W_ru = (const float*)d_in[8];
  const float* dec_a_ru = (const float*)d_in[9];
  const float* dec_b_ru = (const float*)d_in[10];
  const float* dec_W_c  = (const float*)d_in[11];
  const float* dec_a_c  = (const float*)d_in[12];
  const float* dec_b_c  = (const float*)d_in[13];
  const float* proj_W   = (const float*)d_in[14];
  const float* proj_b   = (const float*)d_in[15];
  float* out = (float*)d_out;

  char* ws = (char*)d_ws;
  int*   cnt    = (int*)ws;                    // 512*4        = 2048
  int*   idx    = (int*)(ws + 2048);           // 512*128*4    = 262144
  float* h      = (float*)(ws + 264192);       // 16*512*64*4  = 2097152
  float* h_ru   = (float*)(ws + 2361344);      // 16*512*128*4 = 4194304
  float* src_ru = (float*)(ws + 6555648);      // 32768
  float* dst_ru = (float*)(ws + 6588416);      // 32768
  float* h_c    = (float*)(ws + 6621184);      // 2097152
  float* src_c  = (float*)(ws + 8718336);      // 32768
  float* dst_c  = (float*)(ws + 8751104);      // 32768
  float* u_buf  = (float*)(ws + 8783872);      // 2097152
  float* y_buf  = (float*)(ws + 10881024);     // 32768 (end 10913792)

  hipMemsetAsync(y_buf, 0, NB * NN * sizeof(float), stream);
  k_adj<<<NN, 64, 0, stream>>>(adj, cnt, idx);

  const int GRID = (NB * NN) / WPB;  // 1024 blocks, 8 waves/block, 1 node/wave

  // init: h = 0, compute h_ru(x_0) with encoder weights
  k_phaseA<0, 2, 0, 0><<<GRID, 512, 0, stream>>>(cnt, idx, h_c, src_c, dst_c,
      enc_b_c, u_buf, h, proj_W, proj_b, nullptr, y_buf,
      inputs, enc_W_ru, enc_a_ru, h_ru, src_ru, dst_ru);

  for (int t = 0; t < 12; ++t) {
    k_phaseB<2><<<GRID, 512, 0, stream>>>(cnt, idx, h_ru, src_ru, dst_ru, enc_b_ru,
        h, inputs + (size_t)t * NB * NN * 2, enc_W_c, enc_a_c,
        h_c, src_c, dst_c, u_buf);
    if (t < 11)
      k_phaseA<1, 2, 0, 0><<<GRID, 512, 0, stream>>>(cnt, idx, h_c, src_c, dst_c,
          enc_b_c, u_buf, h, proj_W, proj_b, nullptr, y_buf,
          inputs + (size_t)(t + 1) * NB * NN * 2, enc_W_ru, enc_a_ru,
          h_ru, src_ru, dst_ru);
    else  // last encoder cell: prepare decoder cell 0 (x = GO = zeros)
      k_phaseA<1, 1, 1, 0><<<GRID, 512, 0, stream>>>(cnt, idx, h_c, src_c, dst_c,
          enc_b_c, u_buf, h, proj_W, proj_b, nullptr, y_buf,
          nullptr, dec_W_ru, dec_a_ru, h_ru, src_ru, dst_ru);
  }

  for (int k = 0; k < 12; ++k) {
    k_phaseB<1><<<GRID, 512, 0, stream>>>(cnt, idx, h_ru, src_ru, dst_ru, dec_b_ru,
        h, y_buf, dec_W_c, dec_a_c, h_c, src_c, dst_c, u_buf);
    if (k < 11)
      k_phaseA<1, 1, 2, 1><<<GRID, 512, 0, stream>>>(cnt, idx, h_c, src_c, dst_c,
          dec_b_c, u_buf, h, proj_W, proj_b, out + (size_t)k * NB * NN, y_buf,
          nullptr, dec_W_ru, dec_a_ru, h_ru, src_ru, dst_ru);
    else
      k_phaseA<1, 0, 1, 1><<<GRID, 512, 0, stream>>>(cnt, idx, h_c, src_c, dst_c,
          dec_b_c, u_buf, h, proj_W, proj_b, out + (size_t)k * NB * NN, y_buf,
          nullptr, dec_W_ru, dec_a_ru, h_ru, src_ru, dst_ru);
  }
}

// Round 7
// 801.670 us; speedup vs baseline: 2.6119x; 1.2880x over previous
//
#include <hip/hip_runtime.h>
#include <math.h>

// GARNN: graph-attention GRU, B=16, N=512, U=64, SEQ=12, HORIZON=12, all f32.
// R7 = R4 (best known, 905us) + XCD-aware block swizzle: batch b's blocks all
// land on XCD b/2 (blockIdx%8 = XCD heuristic), so per-XCD L2 working set is
// ~1.3MB (2 batches) instead of ~7MB (all 16) -> gathers hit local L2, not L3.
// Launch bounds stay (512,6): R3/R6 showed capping VGPRs (512,8 -> 32 VGPR)
// destroys the 16-deep load pipeline.

#define NB 16
#define NN 512
#define NU 64
#define CAP 128   // neighbor-list capacity (Bin(511,0.1) max << 128)
#define WPB 8     // waves (=nodes) per block

#define AS1 __attribute__((address_space(1)))
#define AS3 __attribute__((address_space(3)))

__device__ __forceinline__ void ld_lds16(float* lds_uniform, const float* g_perlane) {
#if __has_builtin(__builtin_amdgcn_global_load_lds)
  __builtin_amdgcn_global_load_lds((const AS1 unsigned int*)g_perlane,
                                   (AS3 unsigned int*)lds_uniform, 16, 0, 0);
#else
  int lane = threadIdx.x & 63;
  *(float4*)(lds_uniform + lane * 4) = *(const float4*)(g_perlane);
#endif
}

// Async-stage TB bytes of weights into sW. Wave w handles chunks c = w, w+8, ...
__device__ __forceinline__ void stage_weights(float* sW, const float* W, int TB,
                                              int w, int lane) {
  for (int c = w; c * 1024 < TB; c += WPB) {
    int off = c * 1024 + lane * 16;
    if (off < TB)
      ld_lds16((float*)((char*)sW + c * 1024), (const float*)((const char*)W + off));
  }
}

__device__ __forceinline__ float rlane(float v, int l) {
  return __int_as_float(__builtin_amdgcn_readlane(__float_as_int(v), l));
}
__device__ __forceinline__ int rlane_i(int v, int l) {
  return __builtin_amdgcn_readlane(v, l);
}
__device__ __forceinline__ float wave_max(float v) {
  #pragma unroll
  for (int s = 1; s < 64; s <<= 1) v = fmaxf(v, __shfl_xor(v, s));
  return v;
}
__device__ __forceinline__ float wave_sum(float v) {
  #pragma unroll
  for (int s = 1; s < 64; s <<= 1) v += __shfl_xor(v, s);
  return v;
}
__device__ __forceinline__ void wave_sum2(float& x, float& y) {
  #pragma unroll
  for (int s = 1; s < 64; s <<= 1) { x += __shfl_xor(x, s); y += __shfl_xor(y, s); }
}
__device__ __forceinline__ float fast_rcp(float x) {
#if __has_builtin(__builtin_amdgcn_rcpf)
  return __builtin_amdgcn_rcpf(x);
#else
  return 1.0f / x;
#endif
}
__device__ __forceinline__ float sigmoid_f(float x) {
  return fast_rcp(1.0f + __expf(-x));
}
__device__ __forceinline__ float tanh_f(float x) {
  return 1.0f - 2.0f * fast_rcp(__expf(2.0f * x) + 1.0f);
}

// XCD-aware decode: blockIdx%8 selects XCD (dispatch heuristic). Give XCD x
// batches {2x, 2x+1}; k>>6 picks which, k&63 is the node-chunk. Bijective over
// 1024 blocks. Perf-only heuristic: wrong mapping costs speed, not correctness.
__device__ __forceinline__ void decode_block(int bx, int w, int& b, int& i) {
  int x = bx & 7, k = bx >> 3;
  b = (x << 1) | (k >> 6);
  i = ((k & 63) << 3) | w;
}

// Neighbor lists: mask[i][j] = adj[i][j] > 0.9 || i == j, ascending j.
// Pad tail [cnt, CAP) with j=i so gather loops run unpredicated (p=0 there).
__global__ __launch_bounds__(64) void k_adj(const float* __restrict__ adj,
                                            int* __restrict__ cnt,
                                            int* __restrict__ idx) {
  int i = blockIdx.x;
  int l = threadIdx.x;
  int base = 0;
  #pragma unroll
  for (int c = 0; c < 8; ++c) {
    int j = c * 64 + l;
    bool pred = (adj[i * NN + j] > 0.9f) || (j == i);
    unsigned long long m = __ballot(pred);
    int pos = base + __popcll(m & ((1ull << l) - 1ull));
    if (pred && pos < CAP) idx[i * CAP + pos] = j;
    base += __popcll(m);
  }
  int total = base > CAP ? CAP : base;
  for (int p = total + l; p < CAP; p += 64) idx[i * CAP + p] = i;  // pad
  if (l == 0) cnt[i] = total;
}

// Phase B: ru-attention -> r,u ; write u; h_c = [x, r*h] @ W_c; src_c/dst_c.
template <int DIN>
__global__ __launch_bounds__(512, 6) void k_phaseB(
    const int* __restrict__ cnt, const int* __restrict__ idx,
    const float* __restrict__ h_ru, const float* __restrict__ src_ru,
    const float* __restrict__ dst_ru, const float* __restrict__ b_ru,
    const float* __restrict__ h, const float* __restrict__ x_ptr,
    const float* __restrict__ W_c, const float* __restrict__ a_c,
    float* __restrict__ h_c, float* __restrict__ src_c,
    float* __restrict__ dst_c, float* __restrict__ u_buf) {
  constexpr int TB = (DIN + NU) * NU * 4;
  __shared__ float sW[(DIN + NU) * NU];
  __shared__ float sh[WPB * NU];    // per-wave r*h broadcast
  const int tid = threadIdx.x;
  const int w = tid >> 6, lane = tid & 63;

  stage_weights(sW, W_c, TB, w, lane);   // async; drained at the barrier below

  int b, i;
  decode_block(blockIdx.x, w, b, i);
  const int base_bi = (b << 9) + i;
  const float* __restrict__ hrb = h_ru + ((size_t)b << 16);
  const float* __restrict__ drb = dst_ru + (b << 9);

  const int c_ = cnt[i];
  const float si = src_ru[base_bi];
  const int j0 = idx[(i << 7) + lane];
  const int j1 = idx[(i << 7) + 64 + lane];
  float e0 = -1e30f, e1 = -1e30f;
  if (lane < c_)      { float t = si + drb[j0]; e0 = t >= 0.f ? t : 0.2f * t; }
  if (lane + 64 < c_) { float t = si + drb[j1]; e1 = t >= 0.f ? t : 0.2f * t; }
  float m = wave_max(fmaxf(e0, e1));
  float p0 = (lane < c_) ? __expf(e0 - m) : 0.f;
  float p1 = (lane + 64 < c_) ? __expf(e1 - m) : 0.f;
  float inv = fast_rcp(wave_sum(p0 + p1));
  p0 *= inv; p1 *= inv;

  // aggregation: ru[g] over neighbors, g = 2*lane, 2*lane+1.
  // 16-deep register prefetch: 16 independent loads in flight per group.
  const int g0 = lane << 1;
  float A0 = 0.f, A1 = 0.f, B0 = 0.f, B1 = 0.f;
  const int cc = (c_ + 15) & ~15;
  for (int base = 0; base < cc; base += 16) {
    float2 hv[16];
    #pragma unroll
    for (int q = 0; q < 16; ++q) {
      int jj = base + q;
      int sl = jj & 63;
      int j = (jj < 64) ? rlane_i(j0, sl) : rlane_i(j1, sl);
      hv[q] = *(const float2*)(hrb + (j << 7) + g0);
    }
    #pragma unroll
    for (int q = 0; q < 16; ++q) {
      int jj = base + q;
      int sl = jj & 63;
      float pv = (jj < 64) ? rlane(p0, sl) : rlane(p1, sl);
      if (q & 1) { B0 = fmaf(pv, hv[q].x, B0); B1 = fmaf(pv, hv[q].y, B1); }
      else       { A0 = fmaf(pv, hv[q].x, A0); A1 = fmaf(pv, hv[q].y, A1); }
    }
  }
  A0 += B0; A1 += B1;

  const float2 br = *(const float2*)(b_ru + g0);
  const float ru0 = sigmoid_f(A0 + br.x);
  const float ru1 = sigmoid_f(A1 + br.y);

  // lanes 0..31: r (g<64) -> r*h into LDS; lanes 32..63: u -> global
  if (lane < 32) {
    float2 hh = *(const float2*)(h + ((size_t)base_bi << 6) + g0);
    *(float2*)&sh[(w << 6) + g0] = make_float2(ru0 * hh.x, ru1 * hh.y);
  } else {
    *(float2*)(u_buf + ((size_t)base_bi << 6) + (g0 - 64)) = make_float2(ru0, ru1);
  }

  __syncthreads();   // drains async weight stage + sh visibility

  // h_c GEMV over xc = [x, r*h]; output feature = lane
  float acc;
  if (DIN == 2) {
    float2 xv = *(const float2*)(x_ptr + ((size_t)base_bi << 1));
    acc = xv.x * sW[lane];
    acc = fmaf(xv.y, sW[NU + lane], acc);
  } else {
    acc = x_ptr[base_bi] * sW[lane];
  }
  const float* __restrict__ sWh = sW + DIN * NU;
  const float* shw = sh + (w << 6);
  #pragma unroll
  for (int f2 = 0; f2 < 32; ++f2) {
    float2 rv = *(const float2*)(shw + 2 * f2);   // b64 broadcast
    acc = fmaf(rv.x, sWh[(2 * f2) * NU + lane], acc);
    acc = fmaf(rv.y, sWh[(2 * f2 + 1) * NU + lane], acc);
  }
  h_c[((size_t)base_bi << 6) + lane] = acc;
  float s0 = acc * a_c[lane];
  float s1 = acc * a_c[NU + lane];
  wave_sum2(s0, s1);
  if (lane == 0) { src_c[base_bi] = s0; dst_c[base_bi] = s1; }
}

// Phase A: c-attention -> c; h_new = u*h + (1-u)*c (UPD) or 0 (init);
// OUT: proj -> out+y_buf; DIN_NEXT>0: next cell h_ru = [x_next, h_new] @ W_ru.
template <int UPD, int DIN_NEXT, int XMODE, int OUT>
__global__ __launch_bounds__(512, 6) void k_phaseA(
    const int* __restrict__ cnt, const int* __restrict__ idx,
    const float* __restrict__ h_c, const float* __restrict__ src_c,
    const float* __restrict__ dst_c, const float* __restrict__ b_c,
    const float* __restrict__ u_buf, float* __restrict__ h,
    const float* __restrict__ proj_W, const float* __restrict__ proj_b,
    float* __restrict__ out_slice, float* __restrict__ y_buf,
    const float* __restrict__ x_ptr,
    const float* __restrict__ W_ru, const float* __restrict__ a_ru,
    float* __restrict__ h_ru, float* __restrict__ src_ru,
    float* __restrict__ dst_ru) {
  constexpr int SWN = (DIN_NEXT > 0) ? (DIN_NEXT + NU) * 128 : 1;
  constexpr int TB = (DIN_NEXT > 0) ? SWN * 4 : 0;
  __shared__ float sW[SWN];
  __shared__ float sh[WPB * NU];
  const int tid = threadIdx.x;
  const int w = tid >> 6, lane = tid & 63;

  if (DIN_NEXT > 0) stage_weights(sW, W_ru, TB, w, lane);  // async

  int b, i;
  decode_block(blockIdx.x, w, b, i);
  const int base_bi = (b << 9) + i;

  float hn = 0.f;
  if (UPD) {
    const float* __restrict__ hcb = h_c + ((size_t)b << 15);
    const float* __restrict__ dcb = dst_c + (b << 9);
    const int c_ = cnt[i];
    const float si = src_c[base_bi];
    const int j0 = idx[(i << 7) + lane];
    const int j1 = idx[(i << 7) + 64 + lane];
    float e0 = -1e30f, e1 = -1e30f;
    if (lane < c_)      { float t = si + dcb[j0]; e0 = t >= 0.f ? t : 0.2f * t; }
    if (lane + 64 < c_) { float t = si + dcb[j1]; e1 = t >= 0.f ? t : 0.2f * t; }
    float m = wave_max(fmaxf(e0, e1));
    float p0 = (lane < c_) ? __expf(e0 - m) : 0.f;
    float p1 = (lane + 64 < c_) ? __expf(e1 - m) : 0.f;
    float inv = fast_rcp(wave_sum(p0 + p1));
    p0 *= inv; p1 *= inv;

    float A = 0.f, Bacc = 0.f;
    const int cc = (c_ + 15) & ~15;
    for (int base = 0; base < cc; base += 16) {
      float hv[16];
      #pragma unroll
      for (int q = 0; q < 16; ++q) {
        int jj = base + q;
        int sl = jj & 63;
        int j = (jj < 64) ? rlane_i(j0, sl) : rlane_i(j1, sl);
        hv[q] = hcb[(j << 6) + lane];
      }
      #pragma unroll
      for (int q = 0; q < 16; ++q) {
        int jj = base + q;
        int sl = jj & 63;
        float pv = (jj < 64) ? rlane(p0, sl) : rlane(p1, sl);
        if (q & 1) Bacc = fmaf(pv, hv[q], Bacc);
        else       A = fmaf(pv, hv[q], A);
      }
    }
    A += Bacc;
    const float cc_ = tanh_f(A + b_c[lane]);
    const float u = u_buf[((size_t)base_bi << 6) + lane];
    const float ho = h[((size_t)base_bi << 6) + lane];
    hn = fmaf(u, ho - cc_, cc_);   // u*ho + (1-u)*cc
  }
  h[((size_t)base_bi << 6) + lane] = hn;
  sh[(w << 6) + lane] = hn;        // wave-private broadcast buffer

  float y = 0.f;
  if (OUT) {
    float t = wave_sum(hn * proj_W[lane]);
    y = t + proj_b[0];
    if (lane == 0) { out_slice[base_bi] = y; y_buf[base_bi] = y; }
  }

  if (DIN_NEXT > 0) {
    __syncthreads();   // drains async weight stage; sh written above
    const int g0 = lane << 1;
    float a0, a1;
    if (XMODE == 0) {
      if (DIN_NEXT == 2) {
        float2 xv = *(const float2*)(x_ptr + ((size_t)base_bi << 1));
        a0 = xv.x * sW[g0];
        a1 = xv.x * sW[g0 + 1];
        a0 = fmaf(xv.y, sW[128 + g0], a0);
        a1 = fmaf(xv.y, sW[128 + g0 + 1], a1);
      } else {
        float xv = x_ptr[base_bi];
        a0 = xv * sW[g0]; a1 = xv * sW[g0 + 1];
      }
    } else if (XMODE == 2) {
      a0 = y * sW[g0]; a1 = y * sW[g0 + 1];
    } else {  // XMODE==1: decoder GO token (zeros)
      a0 = 0.f; a1 = 0.f;
    }
    const float* __restrict__ sWh = sW + DIN_NEXT * 128;
    const float* shw = sh + (w << 6);
    #pragma unroll
    for (int f2 = 0; f2 < 32; ++f2) {
      float2 hp = *(const float2*)(shw + 2 * f2);          // b64 broadcast
      float2 w0 = *(const float2*)(sWh + (2 * f2) * 128 + g0);
      float2 w1 = *(const float2*)(sWh + (2 * f2 + 1) * 128 + g0);
      a0 = fmaf(hp.x, w0.x, a0); a1 = fmaf(hp.x, w0.y, a1);
      a0 = fmaf(hp.y, w1.x, a0); a1 = fmaf(hp.y, w1.y, a1);
    }
    *(float2*)(h_ru + ((size_t)base_bi << 7) + g0) = make_float2(a0, a1);
    const float2 ar0 = *(const float2*)(a_ru + g0);
    const float2 ar1 = *(const float2*)(a_ru + 128 + g0);
    float s0 = a0 * ar0.x + a1 * ar0.y;
    float s1 = a0 * ar1.x + a1 * ar1.y;
    wave_sum2(s0, s1);
    if (lane == 0) { src_ru[base_bi] = s0; dst_ru[base_bi] = s1; }
  }
}

extern "C" void kernel_launch(void* const* d_in, const int* in_sizes, int n_in,
                              void* d_out, int out_size, void* d_ws, size_t ws_size,
                              hipStream_t stream) {
  (void)in_sizes; (void)n_in; (void)out_size; (void)ws_size;
  const float* inputs   = (const float*)d_in[0];
  const float* adj      = (const float*)d_in[1];
  const float* enc_W_ru = (const float*)d_in[2];
  const float* enc_a_ru = (const float*)d_in[3];
  const float* enc_b_ru = (const float*)d_in[4];
  const float* enc_W_c  = (const float*)d_in[5];
  const float* enc_a_c  = (const float*)d_in[6];
  const float* enc_b_c  = (const float*)d_in[7];
  const float* dec_W_ru = (const float*)d_in[8];
  const float* dec_a_ru = (const float*)d_in[9];
  const float* dec_b_ru = (const float*)d_in[10];
  const float* dec_W_c  = (const float*)d_in[11];
  const float* dec_a_c  = (const float*)d_in[12];
  const float* dec_b_c  = (const float*)d_in[13];
  const float* proj_W   = (const float*)d_in[14];
  const float* proj_b   = (const float*)d_in[15];
  float* out = (float*)d_out;

  char* ws = (char*)d_ws;
  int*   cnt    = (int*)ws;                    // 512*4        = 2048
  int*   idx    = (int*)(ws + 2048);           // 512*128*4    = 262144
  float* h      = (float*)(ws + 264192);       // 16*512*64*4  = 2097152
  float* h_ru   = (float*)(ws + 2361344);      // 16*512*128*4 = 4194304
  float* src_ru = (float*)(ws + 6555648);      // 32768
  float* dst_ru = (float*)(ws + 6588416);      // 32768
  float* h_c    = (float*)(ws + 6621184);      // 2097152
  float* src_c  = (float*)(ws + 8718336);      // 32768
  float* dst_c  = (float*)(ws + 8751104);      // 32768
  float* u_buf  = (float*)(ws + 8783872);      // 2097152
  float* y_buf  = (float*)(ws + 10881024);     // 32768 (end 10913792)

  hipMemsetAsync(y_buf, 0, NB * NN * sizeof(float), stream);
  k_adj<<<NN, 64, 0, stream>>>(adj, cnt, idx);

  const int GRID = (NB * NN) / WPB;  // 1024 blocks, 8 waves/block, 1 node/wave

  // init: h = 0, compute h_ru(x_0) with encoder weights
  k_phaseA<0, 2, 0, 0><<<GRID, 512, 0, stream>>>(cnt, idx, h_c, src_c, dst_c,
      enc_b_c, u_buf, h, proj_W, proj_b, nullptr, y_buf,
      inputs, enc_W_ru, enc_a_ru, h_ru, src_ru, dst_ru);

  for (int t = 0; t < 12; ++t) {
    k_phaseB<2><<<GRID, 512, 0, stream>>>(cnt, idx, h_ru, src_ru, dst_ru, enc_b_ru,
        h, inputs + (size_t)t * NB * NN * 2, enc_W_c, enc_a_c,
        h_c, src_c, dst_c, u_buf);
    if (t < 11)
      k_phaseA<1, 2, 0, 0><<<GRID, 512, 0, stream>>>(cnt, idx, h_c, src_c, dst_c,
          enc_b_c, u_buf, h, proj_W, proj_b, nullptr, y_buf,
          inputs + (size_t)(t + 1) * NB * NN * 2, enc_W_ru, enc_a_ru,
          h_ru, src_ru, dst_ru);
    else  // last encoder cell: prepare decoder cell 0 (x = GO = zeros)
      k_phaseA<1, 1, 1, 0><<<GRID, 512, 0, stream>>>(cnt, idx, h_c, src_c, dst_c,
          enc_b_c, u_buf, h, proj_W, proj_b, nullptr, y_buf,
          nullptr, dec_W_ru, dec_a_ru, h_ru, src_ru, dst_ru);
  }

  for (int k = 0; k < 12; ++k) {
    k_phaseB<1><<<GRID, 512, 0, stream>>>(cnt, idx, h_ru, src_ru, dst_ru, dec_b_ru,
        h, y_buf, dec_W_c, dec_a_c, h_c, src_c, dst_c, u_buf);
    if (k < 11)
      k_phaseA<1, 1, 2, 1><<<GRID, 512, 0, stream>>>(cnt, idx, h_c, src_c, dst_c,
          dec_b_c, u_buf, h, proj_W, proj_b, out + (size_t)k * NB * NN, y_buf,
          nullptr, dec_W_ru, dec_a_ru, h_ru, src_ru, dst_ru);
    else
      k_phaseA<1, 0, 1, 1><<<GRID, 512, 0, stream>>>(cnt, idx, h_c, src_c, dst_c,
          dec_b_c, u_buf, h, proj_W, proj_b, out + (size_t)k * NB * NN, y_buf,
          nullptr, dec_W_ru, dec_a_ru, h_ru, src_ru, dst_ru);
  }
}